// Round 7
// baseline (1514.624 us; speedup 1.0000x reference)
//
#include <hip/hip_runtime.h>
#include <cstdint>
#include <cstddef>

// Problem constants
#define BATCH   8
#define KPTS    8192
#define NPT     1024
#define NSAMP   16
#define RAD2    0.09f

typedef float f32x2 __attribute__((ext_vector_type(2)));

// DPP max-reduce step for packed u64 (hi=float bits, lo=8191-idx).
// bound_ctrl=true -> out-of-range source lanes read 0 (neutral for unsigned max).
template <int CTRL>
__device__ __forceinline__ unsigned long long dpp_max_step(unsigned long long v) {
    unsigned int lo = (unsigned int)v, hi = (unsigned int)(v >> 32);
    unsigned int lo2 = (unsigned int)__builtin_amdgcn_update_dpp(0, (int)lo, CTRL, 0xf, 0xf, true);
    unsigned int hi2 = (unsigned int)__builtin_amdgcn_update_dpp(0, (int)hi, CTRL, 0xf, 0xf, true);
    unsigned long long o = ((unsigned long long)hi2 << 32) | lo2;
    return o > v ? o : v;
}

// Packed-f32 distance update: d = (px-c)^2 sums with NumPy rounding.
// v_pk_add/v_pk_mul are per-component IEEE ops == scalar rounding; subtraction
// is add of exact negation (IEEE-identical). min/max stay scalar (no pk_min_f32).
__device__ __forceinline__ void upd_pair(const f32x2 px, const f32x2 py, const f32x2 pz,
                                         const f32x2 ncx, const f32x2 ncy, const f32x2 ncz,
                                         f32x2& dmn, f32x2& mm) {
    f32x2 dx, dy, dz, sx, sy, sz, s01, s;
    asm("v_pk_add_f32 %0, %1, %2" : "=v"(dx) : "v"(px), "v"(ncx));
    asm("v_pk_add_f32 %0, %1, %2" : "=v"(dy) : "v"(py), "v"(ncy));
    asm("v_pk_add_f32 %0, %1, %2" : "=v"(dz) : "v"(pz), "v"(ncz));
    asm("v_pk_mul_f32 %0, %1, %1" : "=v"(sx) : "v"(dx));
    asm("v_pk_mul_f32 %0, %1, %1" : "=v"(sy) : "v"(dy));
    asm("v_pk_mul_f32 %0, %1, %1" : "=v"(sz) : "v"(dz));
    asm("v_pk_add_f32 %0, %1, %2" : "=v"(s01) : "v"(sx), "v"(sy));
    asm("v_pk_add_f32 %0, %1, %2" : "=v"(s)   : "v"(s01), "v"(sz));
    dmn.x = fminf(dmn.x, s.x);
    dmn.y = fminf(dmn.y, s.y);
    mm.x  = fmaxf(mm.x, dmn.x);
    mm.y  = fmaxf(mm.y, dmn.y);
}

// ---------------------------------------------------------------------------
// Fused FPS + F0 dispatch, 512 threads/block.
// Blocks 0..7: FPS (one per batch, 16 pts/thread, coords register-resident).
// Blocks 8..519: F0 pre-gather GEMM tiles (128x128, 4x8 acc/thread).
// FPS: packed-u64 DPP wave argmax, cross-wave combine via ONE LDS
// ds_max_u64 per wave into a 3-slot rotating cell (3 slots => tid0's reset
// one-iteration-ahead never races with reads/writes across barrier regions).
// ONE barrier/iter; zero global ops in loop; epilogue writes new_xyz.
// ---------------------------------------------------------------------------
__global__ __launch_bounds__(512, 1) void fps_f0_kernel(
    const float* __restrict__ xyz, float* __restrict__ new_xyz,
    const float* __restrict__ feats, const float* __restrict__ w0,
    float* __restrict__ f0out) {
    __shared__ float xs[KPTS], ys[KPTS], zs[KPTS];               // 96 KB (fps)
    __shared__ unsigned long long slot3[3];
    __shared__ int   hist[NPT];                                   // 4 KB (fps)
    __shared__ float As[16 * 128];                                // f0
    __shared__ float Bs[16 * 130];                                // f0

    const int tid = threadIdx.x;

    if (blockIdx.x >= 8) {
        // ---------------- F0 GEMM: F0[b,p,o] = sum_c feats[b,c,p]*w0[o,3+c]
        const int bid = blockIdx.x - 8;
        const int b   = bid >> 6;
        const int p0  = (bid & 63) << 7;
        const int rb  = (tid >> 4) << 2;  // 4 rows (points)
        const int ob  = tid & 15;         // col base; cols = ob + 16*c
        const float* fb = feats + (size_t)b * 256 * KPTS;

        float acc[4][8];
#pragma unroll
        for (int r = 0; r < 4; ++r)
#pragma unroll
            for (int c = 0; c < 8; ++c) acc[r][c] = 0.f;

        for (int k0 = 0; k0 < 256; k0 += 16) {
#pragma unroll
            for (int i = 0; i < 4; ++i) {
                int e = tid + (i << 9);
                int kk = e >> 7, pc = e & 127;
                As[kk * 128 + pc] = fb[(size_t)(k0 + kk) * KPTS + p0 + pc];
            }
#pragma unroll
            for (int i = 0; i < 4; ++i) {
                int e = tid + (i << 9);
                int o = e >> 4, kk = e & 15;
                Bs[kk * 130 + o] = w0[o * 259 + 3 + k0 + kk];
            }
            __syncthreads();
#pragma unroll
            for (int kk = 0; kk < 16; ++kk) {
                float a[4], wvv[8];
#pragma unroll
                for (int r = 0; r < 4; ++r) a[r] = As[kk * 128 + rb + r];
#pragma unroll
                for (int c = 0; c < 8; ++c) wvv[c] = Bs[kk * 130 + ob + (c << 4)];
#pragma unroll
                for (int r = 0; r < 4; ++r)
#pragma unroll
                    for (int c = 0; c < 8; ++c) acc[r][c] = fmaf(a[r], wvv[c], acc[r][c]);
            }
            __syncthreads();
        }
#pragma unroll
        for (int r = 0; r < 4; ++r) {
            float* outp = f0out + ((size_t)b * KPTS + p0 + rb + r) * 128 + ob;
#pragma unroll
            for (int c = 0; c < 8; ++c) outp[c << 4] = acc[r][c];
        }
        return;
    }

    // ---------------- FPS ----------------
    {
#pragma clang fp contract(off)
        const int b = blockIdx.x;
        const float* xb = xyz + (size_t)b * KPTS * 3;

        for (int i = tid; i < KPTS; i += 512) {
            xs[i] = xb[i * 3 + 0];
            ys[i] = xb[i * 3 + 1];
            zs[i] = xb[i * 3 + 2];
        }
        if (tid < 3) slot3[tid] = 0ull;
        __syncthreads();

        const int base = tid << 4;  // 16 points per thread (8 float2 pairs)
        f32x2 px[8], py[8], pz[8], dmn[8];
#pragma unroll
        for (int j = 0; j < 8; ++j) {
            int i0 = base + (j << 1);
            px[j] = (f32x2){xs[i0], xs[i0 + 1]};
            py[j] = (f32x2){ys[i0], ys[i0 + 1]};
            pz[j] = (f32x2){zs[i0], zs[i0 + 1]};
            dmn[j] = (f32x2){1e10f, 1e10f};
        }

        int far = 0;
        int m0 = 0, m1 = 1;  // it%3 and (it+1)%3, tracked incrementally
        for (int it = 0; it < NPT; ++it) {
            if (tid == 0) {
                hist[it] = far;
                slot3[m1] = 0ull;  // reset one iteration ahead (3-slot safety)
            }
            const float cx = xs[far], cy = ys[far], cz = zs[far];
            const f32x2 ncx = (f32x2){-cx, -cx};
            const f32x2 ncy = (f32x2){-cy, -cy};
            const f32x2 ncz = (f32x2){-cz, -cz};

            f32x2 mm = (f32x2){-1.0f, -1.0f};
#pragma unroll
            for (int j = 0; j < 8; ++j)
                upd_pair(px[j], py[j], pz[j], ncx, ncy, ncz, dmn[j], mm);
            float lmax = fmaxf(mm.x, mm.y);

            // local first-occurrence index of lmax (always exists)
            int ci = 0x7fffffff;
#pragma unroll
            for (int j = 0; j < 8; ++j) {
                if (dmn[j].x == lmax) ci = min(ci, base + (j << 1));
                if (dmn[j].y == lmax) ci = min(ci, base + (j << 1) + 1);
            }

            // packed: value bits (non-negative -> monotone) | (8191 - idx)
            unsigned long long pk =
                ((unsigned long long)__float_as_uint(lmax) << 32) | (unsigned)(8191 - ci);

            // wave max via DPP (VALU pipe): row_shr 1,2,4,8 then row_bcast15/31
            pk = dpp_max_step<0x111>(pk);
            pk = dpp_max_step<0x112>(pk);
            pk = dpp_max_step<0x114>(pk);
            pk = dpp_max_step<0x118>(pk);
            pk = dpp_max_step<0x142>(pk);
            pk = dpp_max_step<0x143>(pk);  // lane 63 holds wave max

            if ((tid & 63) == 63)
                atomicMax(&slot3[m0], pk);   // ds_max_u64, one per wave
            __syncthreads();  // the single barrier

            unsigned long long g = slot3[m0];
            far = 8191 - (int)(unsigned)(g & 0xffffffffull);

            m0 = m1;
            m1 = (m1 == 2) ? 0 : m1 + 1;
        }

        // Epilogue: write all selected coordinates (hist visible via the
        // loop's final barrier).
        for (int i = tid; i < NPT; i += 512) {
            int idx = hist[i];
            float* o = new_xyz + ((size_t)b * NPT + i) * 3;
            o[0] = xs[idx]; o[1] = ys[idx]; o[2] = zs[idx];
        }
    }
}

// ---------------------------------------------------------------------------
// Ball query: one wave per query (4 queries / 256-thread block).
// First NSAMP indices in ascending index order with d2 < R^2; pad with first.
// ---------------------------------------------------------------------------
__global__ __launch_bounds__(256) void ballq_kernel(const float* __restrict__ xyz,
                                                    const float* __restrict__ new_xyz,
                                                    int* __restrict__ idxout) {
    const int tid  = threadIdx.x;
    const int lane = tid & 63;
    const int q    = (blockIdx.x << 2) + (tid >> 6);
    const int b    = q >> 10;
    const float* xb = xyz + (size_t)b * KPTS * 3;
    const float qx = new_xyz[q * 3 + 0];
    const float qy = new_xyz[q * 3 + 1];
    const float qz = new_xyz[q * 3 + 2];
    int* op = idxout + q * NSAMP;

    int total = 0;
    int first_p = 0;
    for (int c = 0; c < KPTS / 64; ++c) {
        int p = (c << 6) + lane;
        float pxv = xb[p * 3 + 0], pyv = xb[p * 3 + 1], pzv = xb[p * 3 + 2];
        float dx = __fsub_rn(qx, pxv), dy = __fsub_rn(qy, pyv), dz = __fsub_rn(qz, pzv);
        float d2 = __fadd_rn(__fadd_rn(__fmul_rn(dx, dx), __fmul_rn(dy, dy)),
                             __fmul_rn(dz, dz));
        bool pred = d2 < RAD2;
        unsigned long long mask = __ballot(pred);
        if (total == 0 && mask != 0ull) first_p = (c << 6) + (int)__builtin_ctzll(mask);
        if (pred) {
            int rank = (int)__popcll(mask & ((1ull << lane) - 1ull));
            int slot = total + rank;
            if (slot < NSAMP) op[slot] = p;
        }
        total += (int)__popcll(mask);
        if (total >= NSAMP) break;
    }
    if (total < NSAMP && lane >= total && lane < NSAMP) op[lane] = first_p;
}

// ---------------------------------------------------------------------------
// Fused gather + BN0/ReLU + two 128x128 layers (in-place LDS) + maxpool.
// 4 queries (64 rows) per 256-thread block.
// ---------------------------------------------------------------------------
#define HS 129  // LDS row stride for h

__global__ __launch_bounds__(256) void mlp_kernel(
    const float* __restrict__ f0, const int* __restrict__ idxw,
    const float* __restrict__ xyz, const float* __restrict__ new_xyz,
    const float* __restrict__ w0,
    const float* __restrict__ g0, const float* __restrict__ b0,
    const float* __restrict__ m0, const float* __restrict__ v0,
    const float* __restrict__ w1,
    const float* __restrict__ g1, const float* __restrict__ b1a,
    const float* __restrict__ m1, const float* __restrict__ v1,
    const float* __restrict__ w2,
    const float* __restrict__ g2, const float* __restrict__ b2a,
    const float* __restrict__ m2, const float* __restrict__ v2,
    float* __restrict__ featout) {
    const int tid = threadIdx.x;
    const int q0  = blockIdx.x << 2;
    const int b   = q0 >> 10;

    __shared__ float h[64 * HS];
    __shared__ float Wsh[16 * HS];
    __shared__ float gx[64], gy[64], gz[64];
    __shared__ int   pidx[64];
    __shared__ float s0[128], t0[128], wxs[128], wys[128], wzs[128];
    __shared__ float s1[128], t1[128], s2[128], t2[128];

    if (tid < 64) pidx[tid] = idxw[(q0 + (tid >> 4)) * NSAMP + (tid & 15)];
    if (tid < 128) {
        float sc = g0[tid] / sqrtf(v0[tid] + 1e-5f);
        s0[tid] = sc; t0[tid] = b0[tid] - m0[tid] * sc;
        sc = g1[tid] / sqrtf(v1[tid] + 1e-5f);
        s1[tid] = sc; t1[tid] = b1a[tid] - m1[tid] * sc;
        sc = g2[tid] / sqrtf(v2[tid] + 1e-5f);
        s2[tid] = sc; t2[tid] = b2a[tid] - m2[tid] * sc;
        wxs[tid] = w0[tid * 259 + 0];
        wys[tid] = w0[tid * 259 + 1];
        wzs[tid] = w0[tid * 259 + 2];
    }
    __syncthreads();
    if (tid < 64) {
        int p = pidx[tid];
        int q = q0 + (tid >> 4);
        const float* pp = xyz + ((size_t)b * KPTS + p) * 3;
        const float* nq = new_xyz + (size_t)q * 3;
        gx[tid] = (pp[0] - nq[0]) / 0.3f;
        gy[tid] = (pp[1] - nq[1]) / 0.3f;
        gz[tid] = (pp[2] - nq[2]) / 0.3f;
    }
    __syncthreads();

    // Phase A: gather F0 rows + xyz contribution + BN0 + ReLU
#pragma unroll 4
    for (int i = 0; i < 32; ++i) {
        int e = tid + (i << 8);
        int row = e >> 7, o = e & 127;
        int p = pidx[row];
        float v = f0[((size_t)b * KPTS + p) * 128 + o];
        v = fmaf(wxs[o], gx[row], v);
        v = fmaf(wys[o], gy[row], v);
        v = fmaf(wzs[o], gz[row], v);
        v = fmaf(v, s0[o], t0[o]);
        h[row * HS + o] = fmaxf(v, 0.f);
    }
    __syncthreads();

    // Layers 1,2: 64x128 @ 128x128, in-place on h
    const int rb = (tid >> 4) << 2;
    const int ob = tid & 15;
    for (int layer = 0; layer < 2; ++layer) {
        const float* wmat = (layer == 0) ? w1 : w2;
        const float* ssp  = (layer == 0) ? s1 : s2;
        const float* ttp  = (layer == 0) ? t1 : t2;
        float acc[4][8];
#pragma unroll
        for (int r = 0; r < 4; ++r)
#pragma unroll
            for (int c = 0; c < 8; ++c) acc[r][c] = 0.f;

        for (int k0 = 0; k0 < 128; k0 += 16) {
#pragma unroll
            for (int i = 0; i < 8; ++i) {
                int e = tid + (i << 8);
                int o = e >> 4, kk = e & 15;
                Wsh[kk * HS + o] = wmat[o * 128 + k0 + kk];
            }
            __syncthreads();
#pragma unroll
            for (int kk = 0; kk < 16; ++kk) {
                float a[4], wvv[8];
#pragma unroll
                for (int r = 0; r < 4; ++r) a[r] = h[(rb + r) * HS + k0 + kk];
#pragma unroll
                for (int c = 0; c < 8; ++c) wvv[c] = Wsh[kk * HS + ob + (c << 4)];
#pragma unroll
                for (int r = 0; r < 4; ++r)
#pragma unroll
                    for (int c = 0; c < 8; ++c) acc[r][c] = fmaf(a[r], wvv[c], acc[r][c]);
            }
            __syncthreads();
        }
#pragma unroll
        for (int r = 0; r < 4; ++r)
#pragma unroll
            for (int c = 0; c < 8; ++c) {
                int o = ob + (c << 4);
                float v = fmaf(acc[r][c], ssp[o], ttp[o]);
                h[(rb + r) * HS + o] = fmaxf(v, 0.f);
            }
        __syncthreads();
    }

    // maxpool over the 16 samples per query
#pragma unroll
    for (int i = 0; i < 2; ++i) {
        int e = tid + (i << 8);
        int qq = e >> 7, o = e & 127;
        float m = h[(qq * 16) * HS + o];
#pragma unroll
        for (int n = 1; n < 16; ++n) m = fmaxf(m, h[(qq * 16 + n) * HS + o]);
        featout[(size_t)(q0 + qq) * 128 + o] = m;
    }
}

// ---------------------------------------------------------------------------
// Head: FC1(bn,relu) -> FC2(bn,relu) -> FC3 + output assembly.
// ---------------------------------------------------------------------------
__global__ __launch_bounds__(256) void head_kernel(
    const float* __restrict__ feat, const float* __restrict__ new_xyz,
    const float* __restrict__ c1w, const float* __restrict__ c1b,
    const float* __restrict__ c2w, const float* __restrict__ c2b,
    const float* __restrict__ c3w, const float* __restrict__ c3b,
    const float* __restrict__ bg1, const float* __restrict__ bb1,
    const float* __restrict__ bm1, const float* __restrict__ bv1,
    const float* __restrict__ bg2, const float* __restrict__ bb2,
    const float* __restrict__ bm2, const float* __restrict__ bv2,
    const float* __restrict__ msz, float* __restrict__ out) {
    const int tid = threadIdx.x;
    const int q0  = blockIdx.x << 3;
    __shared__ float fs[8][128], n1[8][128], n2[8][128];
    __shared__ float s1[128], t1[128], s2[128], t2[128], ms[54];

#pragma unroll
    for (int i = 0; i < 4; ++i) {
        int e = tid + (i << 8);
        fs[e >> 7][e & 127] = feat[(size_t)q0 * 128 + e];
    }
    if (tid < 128) {
        float sc = bg1[tid] / sqrtf(bv1[tid] + 1e-5f);
        s1[tid] = sc; t1[tid] = bb1[tid] - bm1[tid] * sc;
        sc = bg2[tid] / sqrtf(bv2[tid] + 1e-5f);
        s2[tid] = sc; t2[tid] = bb2[tid] - bm2[tid] * sc;
    }
    if (tid < 54) ms[tid] = msz[tid];
    __syncthreads();

    const int o    = tid & 127;
    const int half = tid >> 7;

    {
        float a[4];
#pragma unroll
        for (int j = 0; j < 4; ++j) a[j] = c1b[o];
        const float* wr = c1w + o * 128;
        for (int k = 0; k < 128; k += 4) {
            float4 w4 = *(const float4*)(wr + k);
#pragma unroll
            for (int j = 0; j < 4; ++j) {
                int qq = half * 4 + j;
                a[j] = fmaf(fs[qq][k + 0], w4.x, a[j]);
                a[j] = fmaf(fs[qq][k + 1], w4.y, a[j]);
                a[j] = fmaf(fs[qq][k + 2], w4.z, a[j]);
                a[j] = fmaf(fs[qq][k + 3], w4.w, a[j]);
            }
        }
#pragma unroll
        for (int j = 0; j < 4; ++j)
            n1[half * 4 + j][o] = fmaxf(fmaf(a[j], s1[o], t1[o]), 0.f);
    }
    __syncthreads();
    {
        float a[4];
#pragma unroll
        for (int j = 0; j < 4; ++j) a[j] = c2b[o];
        const float* wr = c2w + o * 128;
        for (int k = 0; k < 128; k += 4) {
            float4 w4 = *(const float4*)(wr + k);
#pragma unroll
            for (int j = 0; j < 4; ++j) {
                int qq = half * 4 + j;
                a[j] = fmaf(n1[qq][k + 0], w4.x, a[j]);
                a[j] = fmaf(n1[qq][k + 1], w4.y, a[j]);
                a[j] = fmaf(n1[qq][k + 2], w4.z, a[j]);
                a[j] = fmaf(n1[qq][k + 3], w4.w, a[j]);
            }
        }
#pragma unroll
        for (int j = 0; j < 4; ++j)
            n2[half * 4 + j][o] = fmaxf(fmaf(a[j], s2[o], t2[o]), 0.f);
    }
    __syncthreads();
    if (o < 97) {
        float a[4];
#pragma unroll
        for (int j = 0; j < 4; ++j) a[j] = c3b[o];
        const float* wr = c3w + o * 128;
        for (int k = 0; k < 128; k += 4) {
            float4 w4 = *(const float4*)(wr + k);
#pragma unroll
            for (int j = 0; j < 4; ++j) {
                int qq = half * 4 + j;
                a[j] = fmaf(n2[qq][k + 0], w4.x, a[j]);
                a[j] = fmaf(n2[qq][k + 1], w4.y, a[j]);
                a[j] = fmaf(n2[qq][k + 2], w4.z, a[j]);
                a[j] = fmaf(n2[qq][k + 3], w4.w, a[j]);
            }
        }
#pragma unroll
        for (int j = 0; j < 4; ++j) {
            int q = q0 + half * 4 + j;
            float v = a[j];
            if (o >= 2 && o < 5) v += new_xyz[(size_t)q * 3 + (o - 2)];
            else if (o == 6) v *= 3.14159265358979323846f;  // * (pi/NH), NH=1
            else if (o >= 25 && o < 79) v *= ms[o - 25];    // sr * mean_size
            out[(size_t)q * 97 + o] = v;
        }
    }
}

// ---------------------------------------------------------------------------
extern "C" void kernel_launch(void* const* d_in, const int* in_sizes, int n_in,
                              void* d_out, int out_size, void* d_ws, size_t ws_size,
                              hipStream_t stream) {
    const float* xyz      = (const float*)d_in[0];
    const float* features = (const float*)d_in[1];
    const float* w0  = (const float*)d_in[2];
    const float* g0  = (const float*)d_in[3];
    const float* b0  = (const float*)d_in[4];
    const float* m0  = (const float*)d_in[5];
    const float* v0  = (const float*)d_in[6];
    const float* w1  = (const float*)d_in[7];
    const float* g1  = (const float*)d_in[8];
    const float* b1  = (const float*)d_in[9];
    const float* m1  = (const float*)d_in[10];
    const float* v1  = (const float*)d_in[11];
    const float* w2  = (const float*)d_in[12];
    const float* g2  = (const float*)d_in[13];
    const float* b2  = (const float*)d_in[14];
    const float* m2  = (const float*)d_in[15];
    const float* v2  = (const float*)d_in[16];
    const float* c1w = (const float*)d_in[17];
    const float* c1b = (const float*)d_in[18];
    const float* c2w = (const float*)d_in[19];
    const float* c2b = (const float*)d_in[20];
    const float* c3w = (const float*)d_in[21];
    const float* c3b = (const float*)d_in[22];
    const float* bg1 = (const float*)d_in[23];
    const float* bb1 = (const float*)d_in[24];
    const float* bm1 = (const float*)d_in[25];
    const float* bv1 = (const float*)d_in[26];
    const float* bg2 = (const float*)d_in[27];
    const float* bb2 = (const float*)d_in[28];
    const float* bm2 = (const float*)d_in[29];
    const float* bv2 = (const float*)d_in[30];
    const float* msz = (const float*)d_in[31];

    float* F0   = (float*)d_ws;
    float* feat = F0 + (size_t)BATCH * KPTS * 128;
    int*   idxw = (int*)(feat + (size_t)BATCH * NPT * 128);
    float* nxyz = (float*)(idxw + (size_t)BATCH * NPT * NSAMP);
    float* outp = (float*)d_out;

    fps_f0_kernel<<<8 + BATCH * (KPTS / 128), 512, 0, stream>>>(
        xyz, nxyz, features, w0, F0);
    ballq_kernel<<<BATCH * NPT / 4, 256, 0, stream>>>(xyz, nxyz, idxw);
    mlp_kernel  <<<BATCH * NPT / 4, 256, 0, stream>>>(
        F0, idxw, xyz, nxyz, w0, g0, b0, m0, v0,
        w1, g1, b1, m1, v1, w2, g2, b2, m2, v2, feat);
    head_kernel <<<BATCH * NPT / 8, 256, 0, stream>>>(
        feat, nxyz, c1w, c1b, c2w, c2b, c3w, c3b,
        bg1, bb1, bm1, bv1, bg2, bb2, bm2, bv2, msz, outp);
}

// Round 9
// 1252.437 us; speedup vs baseline: 1.2093x; 1.2093x over previous
//
#include <hip/hip_runtime.h>
#include <cstdint>
#include <cstddef>

// Problem constants
#define BATCH   8
#define KPTS    8192
#define NPT     1024
#define NSAMP   16
#define RAD2    0.09f

typedef float f32x2 __attribute__((ext_vector_type(2)));
typedef float f32x4 __attribute__((ext_vector_type(4)));
typedef short s16x4 __attribute__((ext_vector_type(4)));
typedef short s16x8 __attribute__((ext_vector_type(8)));

// float -> bf16 bits, round-to-nearest-even (data has no NaN).
__device__ __forceinline__ unsigned short f2bf(float x) {
    unsigned u = __float_as_uint(x);
    return (unsigned short)((u + 0x7fffu + ((u >> 16) & 1u)) >> 16);
}

// DPP max-reduce step for packed u64 (hi=float bits, lo=8191-idx).
template <int CTRL>
__device__ __forceinline__ unsigned long long dpp_max_step(unsigned long long v) {
    unsigned int lo = (unsigned int)v, hi = (unsigned int)(v >> 32);
    unsigned int lo2 = (unsigned int)__builtin_amdgcn_update_dpp(0, (int)lo, CTRL, 0xf, 0xf, true);
    unsigned int hi2 = (unsigned int)__builtin_amdgcn_update_dpp(0, (int)hi, CTRL, 0xf, 0xf, true);
    unsigned long long o = ((unsigned long long)hi2 << 32) | lo2;
    return o > v ? o : v;
}

// ---------------------------------------------------------------------------
// Fused FPS + F0 dispatch, 512 threads/block (R6 structure — verified).
// ---------------------------------------------------------------------------
__global__ __launch_bounds__(512, 1) void fps_f0_kernel(
    const float* __restrict__ xyz, float* __restrict__ new_xyz,
    const float* __restrict__ feats, const float* __restrict__ w0,
    float* __restrict__ f0out) {
    __shared__ float xs[KPTS], ys[KPTS], zs[KPTS];               // 96 KB (fps)
    __shared__ __align__(16) unsigned long long wslot[2][8];
    __shared__ int   hist[NPT];                                   // 4 KB (fps)
    __shared__ float As[16 * 128];                                // f0
    __shared__ float Bs[16 * 130];                                // f0

    const int tid = threadIdx.x;

    if (blockIdx.x >= 8) {
        // ---------------- F0 GEMM: F0[b,p,o] = sum_c feats[b,c,p]*w0[o,3+c]
        const int bid = blockIdx.x - 8;
        const int b   = bid >> 6;
        const int p0  = (bid & 63) << 7;
        const int rb  = (tid >> 4) << 2;
        const int ob  = tid & 15;
        const float* fb = feats + (size_t)b * 256 * KPTS;

        float acc[4][8];
#pragma unroll
        for (int r = 0; r < 4; ++r)
#pragma unroll
            for (int c = 0; c < 8; ++c) acc[r][c] = 0.f;

        for (int k0 = 0; k0 < 256; k0 += 16) {
#pragma unroll
            for (int i = 0; i < 4; ++i) {
                int e = tid + (i << 9);
                int kk = e >> 7, pc = e & 127;
                As[kk * 128 + pc] = fb[(size_t)(k0 + kk) * KPTS + p0 + pc];
            }
#pragma unroll
            for (int i = 0; i < 4; ++i) {
                int e = tid + (i << 9);
                int o = e >> 4, kk = e & 15;
                Bs[kk * 130 + o] = w0[o * 259 + 3 + k0 + kk];
            }
            __syncthreads();
#pragma unroll
            for (int kk = 0; kk < 16; ++kk) {
                float a[4], wvv[8];
#pragma unroll
                for (int r = 0; r < 4; ++r) a[r] = As[kk * 128 + rb + r];
#pragma unroll
                for (int c = 0; c < 8; ++c) wvv[c] = Bs[kk * 130 + ob + (c << 4)];
#pragma unroll
                for (int r = 0; r < 4; ++r)
#pragma unroll
                    for (int c = 0; c < 8; ++c) acc[r][c] = fmaf(a[r], wvv[c], acc[r][c]);
            }
            __syncthreads();
        }
#pragma unroll
        for (int r = 0; r < 4; ++r) {
            float* outp = f0out + ((size_t)b * KPTS + p0 + rb + r) * 128 + ob;
#pragma unroll
            for (int c = 0; c < 8; ++c) outp[c << 4] = acc[r][c];
        }
        return;
    }

    // ---------------- FPS ----------------
    {
#pragma clang fp contract(off)
        const int b = blockIdx.x;
        const float* xb = xyz + (size_t)b * KPTS * 3;

        for (int i = tid; i < KPTS; i += 512) {
            xs[i] = xb[i * 3 + 0];
            ys[i] = xb[i * 3 + 1];
            zs[i] = xb[i * 3 + 2];
        }
        __syncthreads();

        const int base = tid << 4;  // 16 points per thread (8 float2 pairs)
        f32x2 px[8], py[8], pz[8], dmn[8];
#pragma unroll
        for (int j = 0; j < 8; ++j) {
            int i0 = base + (j << 1);
            px[j] = (f32x2){xs[i0], xs[i0 + 1]};
            py[j] = (f32x2){ys[i0], ys[i0 + 1]};
            pz[j] = (f32x2){zs[i0], zs[i0 + 1]};
            dmn[j] = (f32x2){1e10f, 1e10f};
        }

        int far = 0;
        for (int it = 0; it < NPT; ++it) {
            if (tid == 0) hist[it] = far;   // LDS only — off the vmcnt path
            const float cx = xs[far], cy = ys[far], cz = zs[far];
            const f32x2 cx2 = (f32x2){cx, cx};
            const f32x2 cy2 = (f32x2){cy, cy};
            const f32x2 cz2 = (f32x2){cz, cz};

            f32x2 mm = (f32x2){-1.0f, -1.0f};
#pragma unroll
            for (int j = 0; j < 8; ++j) {
                f32x2 dx = px[j] - cx2;
                f32x2 dy = py[j] - cy2;
                f32x2 dz = pz[j] - cz2;
                f32x2 d  = (dx * dx + dy * dy) + dz * dz;  // rounded squares, seq adds
                f32x2 nd = __builtin_elementwise_min(dmn[j], d);
                dmn[j] = nd;
                mm = __builtin_elementwise_max(mm, nd);
            }
            float lmax = fmaxf(mm.x, mm.y);

            int ci = 0x7fffffff;
#pragma unroll
            for (int j = 0; j < 8; ++j) {
                if (dmn[j].x == lmax) ci = min(ci, base + (j << 1));
                if (dmn[j].y == lmax) ci = min(ci, base + (j << 1) + 1);
            }

            unsigned long long pk =
                ((unsigned long long)__float_as_uint(lmax) << 32) | (unsigned)(8191 - ci);

            pk = dpp_max_step<0x111>(pk);
            pk = dpp_max_step<0x112>(pk);
            pk = dpp_max_step<0x114>(pk);
            pk = dpp_max_step<0x118>(pk);
            pk = dpp_max_step<0x142>(pk);
            pk = dpp_max_step<0x143>(pk);  // lane 63 holds wave max

            if ((tid & 63) == 63) wslot[it & 1][tid >> 6] = pk;
            __syncthreads();  // the single barrier (lgkm-only drain)

            ulonglong2 s01 = *(const ulonglong2*)&wslot[it & 1][0];
            ulonglong2 s23 = *(const ulonglong2*)&wslot[it & 1][2];
            ulonglong2 s45 = *(const ulonglong2*)&wslot[it & 1][4];
            ulonglong2 s67 = *(const ulonglong2*)&wslot[it & 1][6];
            unsigned long long g = s01.x;
            if (s01.y > g) g = s01.y;
            if (s23.x > g) g = s23.x;
            if (s23.y > g) g = s23.y;
            if (s45.x > g) g = s45.x;
            if (s45.y > g) g = s45.y;
            if (s67.x > g) g = s67.x;
            if (s67.y > g) g = s67.y;
            far = 8191 - (int)(unsigned)(g & 0xffffffffull);
        }

        for (int i = tid; i < NPT; i += 512) {
            int idx = hist[i];
            float* o = new_xyz + ((size_t)b * NPT + i) * 3;
            o[0] = xs[idx]; o[1] = ys[idx]; o[2] = zs[idx];
        }
    }
}

// ---------------------------------------------------------------------------
// Ball query: one wave per query (4 queries / 256-thread block). Verified.
// ---------------------------------------------------------------------------
__global__ __launch_bounds__(256) void ballq_kernel(const float* __restrict__ xyz,
                                                    const float* __restrict__ new_xyz,
                                                    int* __restrict__ idxout) {
    const int tid  = threadIdx.x;
    const int lane = tid & 63;
    const int q    = (blockIdx.x << 2) + (tid >> 6);
    const int b    = q >> 10;
    const float* xb = xyz + (size_t)b * KPTS * 3;
    const float qx = new_xyz[q * 3 + 0];
    const float qy = new_xyz[q * 3 + 1];
    const float qz = new_xyz[q * 3 + 2];
    int* op = idxout + q * NSAMP;

    int total = 0;
    int first_p = 0;
    for (int c = 0; c < KPTS / 64; ++c) {
        int p = (c << 6) + lane;
        float pxv = xb[p * 3 + 0], pyv = xb[p * 3 + 1], pzv = xb[p * 3 + 2];
        float dx = __fsub_rn(qx, pxv), dy = __fsub_rn(qy, pyv), dz = __fsub_rn(qz, pzv);
        float d2 = __fadd_rn(__fadd_rn(__fmul_rn(dx, dx), __fmul_rn(dy, dy)),
                             __fmul_rn(dz, dz));
        bool pred = d2 < RAD2;
        unsigned long long mask = __ballot(pred);
        if (total == 0 && mask != 0ull) first_p = (c << 6) + (int)__builtin_ctzll(mask);
        if (pred) {
            int rank = (int)__popcll(mask & ((1ull << lane) - 1ull));
            int slot = total + rank;
            if (slot < NSAMP) op[slot] = p;
        }
        total += (int)__popcll(mask);
        if (total >= NSAMP) break;
    }
    if (total < NSAMP && lane >= total && lane < NSAMP) op[lane] = first_p;
}

// ---------------------------------------------------------------------------
// MLP via bf16 MFMA. 4 queries (64 rows) per 256-thread block; wave w owns
// query w's 16 rows exclusively (no cross-wave h hazards).
// h, W staged in LDS as bf16, stride 136 (272 B = 17*16: 16B-aligned, no pow2).
// Layers 1,2: D = A*B, A-frag = h[m=lane&15][k=quad*8+j] (b128),
// B-frag = Wsh[n=lane&15 (+16t)][k=quad*8+j] (b128, gemm_bt pattern),
// D: col=lane&15, row=quad*4+reg. fp32 accumulate; BN/ReLU fp32.
// Maxpool entirely in registers (lane-local + 2 shfl_xor). 3 full barriers.
// ---------------------------------------------------------------------------
#define HB 136

__global__ __launch_bounds__(256) void mlp_kernel(
    const float* __restrict__ f0, const int* __restrict__ idxw,
    const float* __restrict__ xyz, const float* __restrict__ new_xyz,
    const float* __restrict__ w0,
    const float* __restrict__ g0, const float* __restrict__ b0,
    const float* __restrict__ m0, const float* __restrict__ v0,
    const float* __restrict__ w1,
    const float* __restrict__ g1, const float* __restrict__ b1a,
    const float* __restrict__ m1, const float* __restrict__ v1,
    const float* __restrict__ w2,
    const float* __restrict__ g2, const float* __restrict__ b2a,
    const float* __restrict__ m2, const float* __restrict__ v2,
    float* __restrict__ featout) {
    const int tid = threadIdx.x;
    const int q0  = blockIdx.x << 2;
    const int b   = q0 >> 10;

    __shared__ __align__(16) unsigned short hbf[64 * HB];    // 17.4 KB
    __shared__ __align__(16) unsigned short Wsh[128 * HB];   // 34.8 KB
    __shared__ float gx[64], gy[64], gz[64];
    __shared__ int   pidx[64];
    __shared__ float s0[128], t0[128], wxs[128], wys[128], wzs[128];
    __shared__ float s1[128], t1[128], s2[128], t2[128];

    if (tid < 64) pidx[tid] = idxw[(q0 + (tid >> 4)) * NSAMP + (tid & 15)];
    if (tid < 128) {
        float sc = g0[tid] / sqrtf(v0[tid] + 1e-5f);
        s0[tid] = sc; t0[tid] = b0[tid] - m0[tid] * sc;
        sc = g1[tid] / sqrtf(v1[tid] + 1e-5f);
        s1[tid] = sc; t1[tid] = b1a[tid] - m1[tid] * sc;
        sc = g2[tid] / sqrtf(v2[tid] + 1e-5f);
        s2[tid] = sc; t2[tid] = b2a[tid] - m2[tid] * sc;
        wxs[tid] = w0[tid * 259 + 0];
        wys[tid] = w0[tid * 259 + 1];
        wzs[tid] = w0[tid * 259 + 2];
    }
    __syncthreads();
    if (tid < 64) {
        int p = pidx[tid];
        int q = q0 + (tid >> 4);
        const float* pp = xyz + ((size_t)b * KPTS + p) * 3;
        const float* nq = new_xyz + (size_t)q * 3;
        gx[tid] = (pp[0] - nq[0]) / 0.3f;
        gy[tid] = (pp[1] - nq[1]) / 0.3f;
        gz[tid] = (pp[2] - nq[2]) / 0.3f;
    }
    __syncthreads();

    // Phase A: gather F0 + xyz part + BN0 + ReLU -> hbf (bf16); stage w1 bf16.
#pragma unroll 2
    for (int i = 0; i < 8; ++i) {
        int e = tid + (i << 8);
        int row = e >> 5, o = (e & 31) << 2;
        int p = pidx[row];
        float4 v4 = *(const float4*)(f0 + ((size_t)b * KPTS + p) * 128 + o);
        float gxr = gx[row], gyr = gy[row], gzr = gz[row];
        float r0 = fmaf(wzs[o + 0], gzr, fmaf(wys[o + 0], gyr, fmaf(wxs[o + 0], gxr, v4.x)));
        float r1 = fmaf(wzs[o + 1], gzr, fmaf(wys[o + 1], gyr, fmaf(wxs[o + 1], gxr, v4.y)));
        float r2 = fmaf(wzs[o + 2], gzr, fmaf(wys[o + 2], gyr, fmaf(wxs[o + 2], gxr, v4.z)));
        float r3 = fmaf(wzs[o + 3], gzr, fmaf(wys[o + 3], gyr, fmaf(wxs[o + 3], gxr, v4.w)));
        s16x4 c4;
        c4.x = (short)f2bf(fmaxf(fmaf(r0, s0[o + 0], t0[o + 0]), 0.f));
        c4.y = (short)f2bf(fmaxf(fmaf(r1, s0[o + 1], t0[o + 1]), 0.f));
        c4.z = (short)f2bf(fmaxf(fmaf(r2, s0[o + 2], t0[o + 2]), 0.f));
        c4.w = (short)f2bf(fmaxf(fmaf(r3, s0[o + 3], t0[o + 3]), 0.f));
        *(s16x4*)&hbf[row * HB + o] = c4;
    }
#pragma unroll 4
    for (int i = 0; i < 16; ++i) {
        int e = tid + (i << 8);           // 0..4095
        int o = e >> 5;                    // 0..127
        int kt = (e & 31) << 2;            // 0..124
        float4 w4 = *(const float4*)(w1 + o * 128 + kt);
        s16x4 c4 = { (short)f2bf(w4.x), (short)f2bf(w4.y),
                     (short)f2bf(w4.z), (short)f2bf(w4.w) };
        *(s16x4*)&Wsh[o * HB + kt] = c4;
    }
    __syncthreads();   // barrier 1: hbf + Wsh(w1) ready

    const int w    = tid >> 6;        // wave = query
    const int lane = tid & 63;
    const int l15  = lane & 15;
    const int quad = lane >> 4;
    const int wrow = w << 4;          // this wave's 16 rows

    // ---- Layer 1 MFMA
    f32x4 acc[8];
#pragma unroll
    for (int t = 0; t < 8; ++t) acc[t] = (f32x4){0.f, 0.f, 0.f, 0.f};
#pragma unroll
    for (int k0 = 0; k0 < 128; k0 += 32) {
        s16x8 a = *(const s16x8*)&hbf[(wrow + l15) * HB + k0 + (quad << 3)];
#pragma unroll
        for (int t = 0; t < 8; ++t) {
            s16x8 bf = *(const s16x8*)&Wsh[((t << 4) + l15) * HB + k0 + (quad << 3)];
            acc[t] = __builtin_amdgcn_mfma_f32_16x16x32_bf16(a, bf, acc[t], 0, 0, 0);
        }
    }
    __syncthreads();   // barrier 2: Wsh(w1)/hbf reads done

    // writeback layer1 (bf16, own rows only) + stage w2
#pragma unroll
    for (int t = 0; t < 8; ++t) {
        int o = (t << 4) + l15;
        float ss = s1[o], tt = t1[o];
#pragma unroll
        for (int r = 0; r < 4; ++r) {
            float v = fmaxf(fmaf(acc[t][r], ss, tt), 0.f);
            hbf[(wrow + (quad << 2) + r) * HB + o] = f2bf(v);
        }
    }
#pragma unroll 4
    for (int i = 0; i < 16; ++i) {
        int e = tid + (i << 8);
        int o = e >> 5;
        int kt = (e & 31) << 2;
        float4 w4 = *(const float4*)(w2 + o * 128 + kt);
        s16x4 c4 = { (short)f2bf(w4.x), (short)f2bf(w4.y),
                     (short)f2bf(w4.z), (short)f2bf(w4.w) };
        *(s16x4*)&Wsh[o * HB + kt] = c4;
    }
    __syncthreads();   // barrier 3: hbf(l2 input) + Wsh(w2) ready

    // ---- Layer 2 MFMA
#pragma unroll
    for (int t = 0; t < 8; ++t) acc[t] = (f32x4){0.f, 0.f, 0.f, 0.f};
#pragma unroll
    for (int k0 = 0; k0 < 128; k0 += 32) {
        s16x8 a = *(const s16x8*)&hbf[(wrow + l15) * HB + k0 + (quad << 3)];
#pragma unroll
        for (int t = 0; t < 8; ++t) {
            s16x8 bf = *(const s16x8*)&Wsh[((t << 4) + l15) * HB + k0 + (quad << 3)];
            acc[t] = __builtin_amdgcn_mfma_f32_16x16x32_bf16(a, bf, acc[t], 0, 0, 0);
        }
    }

    // BN2/ReLU + in-register maxpool over the wave's 16 rows (= 1 query)
#pragma unroll
    for (int t = 0; t < 8; ++t) {
        int o = (t << 4) + l15;
        float ss = s2[o], tt = t2[o];
        float m0v = fmaxf(fmaf(acc[t][0], ss, tt), 0.f);
        float m1v = fmaxf(fmaf(acc[t][1], ss, tt), 0.f);
        float m2v = fmaxf(fmaf(acc[t][2], ss, tt), 0.f);
        float m3v = fmaxf(fmaf(acc[t][3], ss, tt), 0.f);
        float m = fmaxf(fmaxf(m0v, m1v), fmaxf(m2v, m3v));
        m = fmaxf(m, __shfl_xor(m, 16));
        m = fmaxf(m, __shfl_xor(m, 32));
        if (quad == 0)
            featout[(size_t)(q0 + w) * 128 + o] = m;
    }
}

// ---------------------------------------------------------------------------
// Head: FC1(bn,relu) -> FC2(bn,relu) -> FC3 + output assembly (fp32, verified).
// ---------------------------------------------------------------------------
__global__ __launch_bounds__(256) void head_kernel(
    const float* __restrict__ feat, const float* __restrict__ new_xyz,
    const float* __restrict__ c1w, const float* __restrict__ c1b,
    const float* __restrict__ c2w, const float* __restrict__ c2b,
    const float* __restrict__ c3w, const float* __restrict__ c3b,
    const float* __restrict__ bg1, const float* __restrict__ bb1,
    const float* __restrict__ bm1, const float* __restrict__ bv1,
    const float* __restrict__ bg2, const float* __restrict__ bb2,
    const float* __restrict__ bm2, const float* __restrict__ bv2,
    const float* __restrict__ msz, float* __restrict__ out) {
    const int tid = threadIdx.x;
    const int q0  = blockIdx.x << 3;
    __shared__ float fs[8][128], n1[8][128], n2[8][128];
    __shared__ float s1[128], t1[128], s2[128], t2[128], ms[54];

#pragma unroll
    for (int i = 0; i < 4; ++i) {
        int e = tid + (i << 8);
        fs[e >> 7][e & 127] = feat[(size_t)q0 * 128 + e];
    }
    if (tid < 128) {
        float sc = bg1[tid] / sqrtf(bv1[tid] + 1e-5f);
        s1[tid] = sc; t1[tid] = bb1[tid] - bm1[tid] * sc;
        sc = bg2[tid] / sqrtf(bv2[tid] + 1e-5f);
        s2[tid] = sc; t2[tid] = bb2[tid] - bm2[tid] * sc;
    }
    if (tid < 54) ms[tid] = msz[tid];
    __syncthreads();

    const int o    = tid & 127;
    const int half = tid >> 7;

    {
        float a[4];
#pragma unroll
        for (int j = 0; j < 4; ++j) a[j] = c1b[o];
        const float* wr = c1w + o * 128;
        for (int k = 0; k < 128; k += 4) {
            float4 w4 = *(const float4*)(wr + k);
#pragma unroll
            for (int j = 0; j < 4; ++j) {
                int qq = half * 4 + j;
                a[j] = fmaf(fs[qq][k + 0], w4.x, a[j]);
                a[j] = fmaf(fs[qq][k + 1], w4.y, a[j]);
                a[j] = fmaf(fs[qq][k + 2], w4.z, a[j]);
                a[j] = fmaf(fs[qq][k + 3], w4.w, a[j]);
            }
        }
#pragma unroll
        for (int j = 0; j < 4; ++j)
            n1[half * 4 + j][o] = fmaxf(fmaf(a[j], s1[o], t1[o]), 0.f);
    }
    __syncthreads();
    {
        float a[4];
#pragma unroll
        for (int j = 0; j < 4; ++j) a[j] = c2b[o];
        const float* wr = c2w + o * 128;
        for (int k = 0; k < 128; k += 4) {
            float4 w4 = *(const float4*)(wr + k);
#pragma unroll
            for (int j = 0; j < 4; ++j) {
                int qq = half * 4 + j;
                a[j] = fmaf(n1[qq][k + 0], w4.x, a[j]);
                a[j] = fmaf(n1[qq][k + 1], w4.y, a[j]);
                a[j] = fmaf(n1[qq][k + 2], w4.z, a[j]);
                a[j] = fmaf(n1[qq][k + 3], w4.w, a[j]);
            }
        }
#pragma unroll
        for (int j = 0; j < 4; ++j)
            n2[half * 4 + j][o] = fmaxf(fmaf(a[j], s2[o], t2[o]), 0.f);
    }
    __syncthreads();
    if (o < 97) {
        float a[4];
#pragma unroll
        for (int j = 0; j < 4; ++j) a[j] = c3b[o];
        const float* wr = c3w + o * 128;
        for (int k = 0; k < 128; k += 4) {
            float4 w4 = *(const float4*)(wr + k);
#pragma unroll
            for (int j = 0; j < 4; ++j) {
                int qq = half * 4 + j;
                a[j] = fmaf(n2[qq][k + 0], w4.x, a[j]);
                a[j] = fmaf(n2[qq][k + 1], w4.y, a[j]);
                a[j] = fmaf(n2[qq][k + 2], w4.z, a[j]);
                a[j] = fmaf(n2[qq][k + 3], w4.w, a[j]);
            }
        }
#pragma unroll
        for (int j = 0; j < 4; ++j) {
            int q = q0 + half * 4 + j;
            float v = a[j];
            if (o >= 2 && o < 5) v += new_xyz[(size_t)q * 3 + (o - 2)];
            else if (o == 6) v *= 3.14159265358979323846f;  // * (pi/NH), NH=1
            else if (o >= 25 && o < 79) v *= ms[o - 25];    // sr * mean_size
            out[(size_t)q * 97 + o] = v;
        }
    }
}

// ---------------------------------------------------------------------------
extern "C" void kernel_launch(void* const* d_in, const int* in_sizes, int n_in,
                              void* d_out, int out_size, void* d_ws, size_t ws_size,
                              hipStream_t stream) {
    const float* xyz      = (const float*)d_in[0];
    const float* features = (const float*)d_in[1];
    const float* w0  = (const float*)d_in[2];
    const float* g0  = (const float*)d_in[3];
    const float* b0  = (const float*)d_in[4];
    const float* m0  = (const float*)d_in[5];
    const float* v0  = (const float*)d_in[6];
    const float* w1  = (const float*)d_in[7];
    const float* g1  = (const float*)d_in[8];
    const float* b1  = (const float*)d_in[9];
    const float* m1  = (const float*)d_in[10];
    const float* v1  = (const float*)d_in[11];
    const float* w2  = (const float*)d_in[12];
    const float* g2  = (const float*)d_in[13];
    const float* b2  = (const float*)d_in[14];
    const float* m2  = (const float*)d_in[15];
    const float* v2  = (const float*)d_in[16];
    const float* c1w = (const float*)d_in[17];
    const float* c1b = (const float*)d_in[18];
    const float* c2w = (const float*)d_in[19];
    const float* c2b = (const float*)d_in[20];
    const float* c3w = (const float*)d_in[21];
    const float* c3b = (const float*)d_in[22];
    const float* bg1 = (const float*)d_in[23];
    const float* bb1 = (const float*)d_in[24];
    const float* bm1 = (const float*)d_in[25];
    const float* bv1 = (const float*)d_in[26];
    const float* bg2 = (const float*)d_in[27];
    const float* bb2 = (const float*)d_in[28];
    const float* bm2 = (const float*)d_in[29];
    const float* bv2 = (const float*)d_in[30];
    const float* msz = (const float*)d_in[31];

    float* F0   = (float*)d_ws;
    float* feat = F0 + (size_t)BATCH * KPTS * 128;
    int*   idxw = (int*)(feat + (size_t)BATCH * NPT * 128);
    float* nxyz = (float*)(idxw + (size_t)BATCH * NPT * NSAMP);
    float* outp = (float*)d_out;

    fps_f0_kernel<<<8 + BATCH * (KPTS / 128), 512, 0, stream>>>(
        xyz, nxyz, features, w0, F0);
    ballq_kernel<<<BATCH * NPT / 4, 256, 0, stream>>>(xyz, nxyz, idxw);
    mlp_kernel  <<<BATCH * NPT / 4, 256, 0, stream>>>(
        F0, idxw, xyz, nxyz, w0, g0, b0, m0, v0,
        w1, g1, b1, m1, v1, w2, g2, b2, m2, v2, feat);
    head_kernel <<<BATCH * NPT / 8, 256, 0, stream>>>(
        feat, nxyz, c1w, c1b, c2w, c2b, c3w, c3b,
        bg1, bb1, bm1, bv1, bg2, bb2, bm2, bv2, msz, outp);
}